// Round 7
// baseline (534.729 us; speedup 1.0000x reference)
//
#include <hip/hip_runtime.h>
#include <math.h>

#define SMK    2048
#define TAPS   32
#define OUTLEN (SMK + TAPS - 1)   // 2079
#define PAD    32
#define SLOTS  (PAD + SMK + PAD)  // 2112 float2 slots
#define MDFT   64
#define ROWS_PER_BLOCK 8
#define NBLOCKS 2048              // * ROWS_PER_BLOCK = 16384 rows

typedef float v2f __attribute__((ext_vector_type(2)));

// Bijective 8B-slot swizzle (round-2/6 proven for 64B-lane-stride window reads).
__device__ __forceinline__ int swz(int p) { return p ^ ((p >> 4) & 15); }

__device__ __forceinline__ float rfl(float x) {
    return __int_as_float(__builtin_amdgcn_readfirstlane(__float_as_int(x)));
}

__global__ __launch_bounds__(256)
__attribute__((amdgpu_waves_per_eu(3, 3)))   // 168-VGPR budget: no spill-at-64 repeat
void conv_kernel(const float* __restrict__ input,
                 const float* __restrict__ cof,
                 float* __restrict__ out0,
                 float* __restrict__ out1)
{
    __shared__ float2 s_sig[SLOTS];
    __shared__ float2 s_tw[MDFT];

    const int tid = threadIdx.x;

    // One-time: zero pads (never overwritten) + DFT twiddles.
    if (tid < PAD) {
        s_sig[swz(tid)] = make_float2(0.f, 0.f);            // front pad [0,32)
    } else if (tid < 2 * PAD) {
        s_sig[swz(SMK + tid)] = make_float2(0.f, 0.f);      // back pad 2080..2111
    }
    if (tid >= 64 && tid < 128) {
        int j = tid - 64;
        float sv, cv;
        __sincosf(-2.0f * (float)M_PI * (float)j / (float)MDFT, &sv, &cv);
        s_tw[j] = make_float2(cv, sv);
    }

    // Prologue: row 0 signal + taps.
    float4 stg[4];
    float  hre[TAPS], him[TAPS];
    {
        const float4* g = (const float4*)(input + (size_t)blockIdx.x * (SMK * 2));
        #pragma unroll
        for (int k = 0; k < 4; ++k) stg[k] = g[tid + 256 * k];
        const float2* ct = (const float2*)(cof + (size_t)blockIdx.x * (TAPS * 2));
        #pragma unroll
        for (int l = 0; l < TAPS; ++l) {
            float2 tv = ct[l];
            hre[l] = rfl(tv.x);
            him[l] = rfl(tv.y);
        }
    }

    #pragma unroll 1
    for (int it = 0; it < ROWS_PER_BLOCK; ++it) {
        const size_t r = (size_t)blockIdx.x + (size_t)NBLOCKS * it;

        __syncthreads();   // prior row's LDS reads complete (it=0: pad writes)
        #pragma unroll
        for (int k = 0; k < 4; ++k) {
            int i0 = PAD + 2 * (tid + 256 * k);
            s_sig[swz(i0)]     = make_float2(stg[k].x, stg[k].y);
            s_sig[swz(i0 + 1)] = make_float2(stg[k].z, stg[k].w);
        }
        __syncthreads();   // row r visible

        // Issue row r+1's loads NOW: they fly under the whole compute phase.
        // Taps are uniform loads (-> s_load); consumed only at the rotate
        // point at loop bottom, so their wait lands after compute too.
        float4 nstg[4];
        float  nhre[TAPS], nhim[TAPS];
        const bool more = (it + 1 < ROWS_PER_BLOCK);
        if (more) {
            const float4* gn = (const float4*)(input + (r + NBLOCKS) * (size_t)(SMK * 2));
            #pragma unroll
            for (int k = 0; k < 4; ++k) nstg[k] = gn[tid + 256 * k];
            const float2* ctn = (const float2*)(cof + (r + NBLOCKS) * (size_t)(TAPS * 2));
            #pragma unroll
            for (int l = 0; l < TAPS; ++l) {
                float2 tv = ctn[l];
                nhre[l] = tv.x;    // uniform; rfl applied at rotate
                nhim[l] = tv.y;
            }
        }

        // ---- compute row r: 8 consecutive outputs/thread (round-6 core) ----
        const int t0 = tid * 8;
        float2 win[39];
        #pragma unroll
        for (int m = 0; m < 39; ++m) win[m] = s_sig[swz(t0 + 1 + m)];

        v2f accA[8], accB[8];
        #pragma unroll
        for (int k = 0; k < 8; ++k) { accA[k] = (v2f)(0.f); accB[k] = (v2f)(0.f); }

        #pragma unroll
        for (int l = 0; l < TAPS; ++l) {
            const v2f hv = { hre[l], him[l] };
            #pragma unroll
            for (int k = 0; k < 8; ++k) {
                const float2 s = win[k + 31 - l];
                accA[k] = __builtin_elementwise_fma((v2f){ s.x, s.x }, hv, accA[k]);
                accB[k] = __builtin_elementwise_fma((v2f){ s.y, s.y }, hv, accB[k]);
            }
        }

        float2* go2 = (float2*)(out0 + r * (size_t)(OUTLEN * 2));
        #pragma unroll
        for (int k = 0; k < 8; ++k)
            go2[t0 + k] = make_float2(accA[k].x - accB[k].y, accA[k].y + accB[k].x);

        // wave 0: fused 64-pt DFT of zero-padded taps
        if (tid < MDFT) {
            const int kk = tid;
            v2f aA = (v2f)(0.f), aB = (v2f)(0.f);
            #pragma unroll
            for (int l = 0; l < TAPS; ++l) {
                const v2f hv = { hre[l], him[l] };
                float2 w = s_tw[(kk * l) & (MDFT - 1)];
                aA = __builtin_elementwise_fma((v2f){ w.x, w.x }, hv, aA);
                aB = __builtin_elementwise_fma((v2f){ w.y, w.y }, hv, aB);
            }
            ((float2*)out1)[r * MDFT + kk] = make_float2(aA.x - aB.y, aA.y + aB.x);
        }
        // wave 2: tail outputs t = 2048..2078
        else if (tid >= 128 && tid < 128 + (OUTLEN - SMK)) {
            const int t = SMK + (tid - 128);
            v2f aA = (v2f)(0.f), aB = (v2f)(0.f);
            #pragma unroll
            for (int l = 0; l < TAPS; ++l) {
                const v2f hv = { hre[l], him[l] };
                float2 s = s_sig[swz(PAD + t - l)];   // back pad supplies zeros
                aA = __builtin_elementwise_fma((v2f){ s.x, s.x }, hv, aA);
                aB = __builtin_elementwise_fma((v2f){ s.y, s.y }, hv, aB);
            }
            go2[t] = make_float2(aA.x - aB.y, aA.y + aB.x);
        }

        // Rotate prefetched row into place (tap waits land here, post-compute).
        if (more) {
            #pragma unroll
            for (int k = 0; k < 4; ++k) stg[k] = nstg[k];
            #pragma unroll
            for (int l = 0; l < TAPS; ++l) {
                hre[l] = rfl(nhre[l]);
                him[l] = rfl(nhim[l]);
            }
        }
    }
}

extern "C" void kernel_launch(void* const* d_in, const int* in_sizes, int n_in,
                              void* d_out, int out_size, void* d_ws, size_t ws_size,
                              hipStream_t stream)
{
    const float* input = (const float*)d_in[0];  // (N,P,2048,2) fp32
    const float* cof   = (const float*)d_in[1];  // (N,P,32,2)   fp32
    // d_in[2] is M (=64), compile-time here.

    const int NP = in_sizes[0] / (SMK * 2);      // 16384

    float* out0 = (float*)d_out;                           // (NP, 2079, 2)
    float* out1 = out0 + (size_t)NP * OUTLEN * 2;          // (NP, 64, 2)

    conv_kernel<<<NBLOCKS, 256, 0, stream>>>(input, cof, out0, out1);
}

// Round 8
// 146.167 us; speedup vs baseline: 3.6584x; 3.6584x over previous
//
#include <hip/hip_runtime.h>
#include <math.h>

#define SMK    2048
#define TAPS   32
#define OUTLEN (SMK + TAPS - 1)   // 2079
#define PAD    32
#define SLOTS  (PAD + SMK + PAD)  // 2112 float2 slots
#define MDFT   64

typedef float v2f __attribute__((ext_vector_type(2)));

// Bijective 8B-slot swizzle (r2/r6 proven conflict-free for the
// 64B-lane-stride window reads).
__device__ __forceinline__ int swz(int p) { return p ^ ((p >> 4) & 15); }

__device__ __forceinline__ float rfl(float x) {
    return __int_as_float(__builtin_amdgcn_readfirstlane(__float_as_int(x)));
}

// NOTE: no waves_per_eu / min-wave hints — they caused spill pathologies in
// r3/r5/r7. K-split caps natural register demand (~95) instead.
__global__ __launch_bounds__(256)
void conv_kernel(const float* __restrict__ input,
                 const float* __restrict__ cof,
                 float* __restrict__ out0,
                 float* __restrict__ out1)
{
    __shared__ float2 s_sig[SLOTS];
    __shared__ float2 s_tw[MDFT];

    const int tid = threadIdx.x;
    const int row = blockIdx.x;

    // ---- stage signal row (16 KB) into swizzled LDS ----
    const float4* gin = (const float4*)(input + (size_t)row * (SMK * 2));
    #pragma unroll
    for (int k = 0; k < 4; ++k) {
        float4 v = gin[tid + 256 * k];
        int i0 = PAD + 2 * (tid + 256 * k);
        s_sig[swz(i0)]     = make_float2(v.x, v.y);
        s_sig[swz(i0 + 1)] = make_float2(v.z, v.w);
    }
    if (tid < PAD) {
        s_sig[swz(tid)] = make_float2(0.f, 0.f);            // front pad
    } else if (tid < 2 * PAD) {
        s_sig[swz(SMK + tid)] = make_float2(0.f, 0.f);      // back pad 2080..2111
    }
    if (tid >= 64 && tid < 128) {                           // twiddles e^{-2pi i j/64}
        int j = tid - 64;
        float sv, cv;
        __sincosf(-2.0f * (float)M_PI * (float)j / (float)MDFT, &sv, &cv);
        s_tw[j] = make_float2(cv, sv);
    }

    // ---- taps -> SGPR (block-uniform via readfirstlane) ----
    const float2* __restrict__ ct = (const float2*)(cof + (size_t)row * (TAPS * 2));
    float hre[TAPS], him[TAPS];
    #pragma unroll
    for (int l = 0; l < TAPS; ++l) {
        float2 tv = ct[l];
        hre[l] = rfl(tv.x);
        him[l] = rfl(tv.y);
    }
    __syncthreads();

    // ---- main: 8 consecutive outputs/thread, taps K-split into 2 chunks ----
    // Live window per chunk: 23 float2 (46 VGPR) instead of 39 (78 VGPR).
    const int t0 = tid * 8;

    v2f accA[8], accB[8];
    #pragma unroll
    for (int k = 0; k < 8; ++k) { accA[k] = (v2f)(0.f); accB[k] = (v2f)(0.f); }

    #pragma unroll
    for (int c = 0; c < 2; ++c) {
        // chunk c covers taps l = 16c .. 16c+15.
        // needed window: sig[t0+k-l] -> slot m = k-l+31 in [16,38] (c=0), [0,22] (c=1)
        // win[j] = slot (16*(1-c) + j), j = 0..22; inner index j = k - lp + 15.
        float2 win[23];
        const int sbase = t0 + 1 + 16 * (1 - c);
        #pragma unroll
        for (int j = 0; j < 23; ++j) win[j] = s_sig[swz(sbase + j)];

        #pragma unroll
        for (int lp = 0; lp < 16; ++lp) {
            const int l = 16 * c + lp;
            const v2f hv = { hre[l], him[l] };     // SGPR pair, uniform
            #pragma unroll
            for (int k = 0; k < 8; ++k) {
                const float2 s = win[k - lp + 15]; // compile-time index
                accA[k] = __builtin_elementwise_fma((v2f){ s.x, s.x }, hv, accA[k]);
                accB[k] = __builtin_elementwise_fma((v2f){ s.y, s.y }, hv, accB[k]);
            }
        }
        // Contain chunk live-ranges: don't let chunk-1 reads hoist above
        // chunk-0 compute (would recreate the 78-reg window).
        __builtin_amdgcn_sched_barrier(0);
    }

    float2* go2 = (float2*)(out0 + (size_t)row * (OUTLEN * 2));
    #pragma unroll
    for (int k = 0; k < 8; ++k)
        go2[t0 + k] = make_float2(accA[k].x - accB[k].y, accA[k].y + accB[k].x);

    // ---- wave 0 extra: fused 64-pt DFT of zero-padded taps ----
    if (tid < MDFT) {
        const int kk = tid;
        v2f aA = (v2f)(0.f), aB = (v2f)(0.f);
        #pragma unroll
        for (int l = 0; l < TAPS; ++l) {
            const v2f hv = { hre[l], him[l] };
            float2 w = s_tw[(kk * l) & (MDFT - 1)];
            aA = __builtin_elementwise_fma((v2f){ w.x, w.x }, hv, aA);
            aB = __builtin_elementwise_fma((v2f){ w.y, w.y }, hv, aB);
        }
        ((float2*)out1)[(size_t)row * MDFT + kk] =
            make_float2(aA.x - aB.y, aA.y + aB.x);
    }
    // ---- wave 2 extra: tail outputs t = 2048..2078 ----
    else if (tid >= 128 && tid < 128 + (OUTLEN - SMK)) {
        const int t = SMK + (tid - 128);
        v2f aA = (v2f)(0.f), aB = (v2f)(0.f);
        #pragma unroll
        for (int l = 0; l < TAPS; ++l) {
            const v2f hv = { hre[l], him[l] };
            float2 s = s_sig[swz(PAD + t - l)];   // back pad supplies zeros
            aA = __builtin_elementwise_fma((v2f){ s.x, s.x }, hv, aA);
            aB = __builtin_elementwise_fma((v2f){ s.y, s.y }, hv, aB);
        }
        go2[t] = make_float2(aA.x - aB.y, aA.y + aB.x);
    }
}

extern "C" void kernel_launch(void* const* d_in, const int* in_sizes, int n_in,
                              void* d_out, int out_size, void* d_ws, size_t ws_size,
                              hipStream_t stream)
{
    const float* input = (const float*)d_in[0];  // (N,P,2048,2) fp32
    const float* cof   = (const float*)d_in[1];  // (N,P,32,2)   fp32
    // d_in[2] is M (=64), compile-time here.

    const int NP = in_sizes[0] / (SMK * 2);      // 16384

    float* out0 = (float*)d_out;                           // (NP, 2079, 2)
    float* out1 = out0 + (size_t)NP * OUTLEN * 2;          // (NP, 64, 2)

    conv_kernel<<<NP, 256, 0, stream>>>(input, cof, out0, out1);
}

// Round 9
// 139.735 us; speedup vs baseline: 3.8267x; 1.0460x over previous
//
#include <hip/hip_runtime.h>
#include <math.h>

#define SMK    2048
#define TAPS   32
#define OUTLEN (SMK + TAPS - 1)   // 2079
#define PAD    32
#define SLOTS  (PAD + SMK + PAD)  // 2112 float2 slots
#define NF4    (SLOTS / 2)        // 1056 float4 slots
#define MDFT   64

typedef float v2f __attribute__((ext_vector_type(2)));

__device__ __forceinline__ float rfl(float x) {
    return __int_as_float(__builtin_amdgcn_readfirstlane(__float_as_int(x)));
}

// Design target: <=64 VGPR so 8 blocks/CU fit (occupancy step is at 64).
// Live set: 6 float4 window (24) + 4x2 v2f acc (16) + addressing ~14 = ~54.
__global__ __launch_bounds__(256, 8)
void conv_kernel(const float* __restrict__ input,
                 const float* __restrict__ cof,
                 float* __restrict__ out0,
                 float* __restrict__ out1)
{
    __shared__ float4 S4[NF4];        // LINEAR layout — no swizzle anywhere
    __shared__ float2 s_tw[MDFT];

    const int tid = threadIdx.x;
    const int row = blockIdx.x;

    // ---- stage signal row (16 KB) into linear LDS ----
    const float4* gin = (const float4*)(input + (size_t)row * (SMK * 2));
    #pragma unroll
    for (int k = 0; k < 4; ++k) S4[16 + tid + 256 * k] = gin[tid + 256 * k];
    if (tid < 16) {
        S4[tid] = make_float4(0.f, 0.f, 0.f, 0.f);            // front pad f2 [0,32)
    } else if (tid < 32) {
        S4[1024 + tid] = make_float4(0.f, 0.f, 0.f, 0.f);     // back pad f2 [2080,2112)
    }
    if (tid >= 64 && tid < 128) {                             // twiddles e^{-2pi i j/64}
        int j = tid - 64;
        float sv, cv;
        __sincosf(-2.0f * (float)M_PI * (float)j / (float)MDFT, &sv, &cv);
        s_tw[j] = make_float2(cv, sv);
    }

    // ---- taps -> SGPR (block-uniform via readfirstlane) ----
    const float2* __restrict__ ct = (const float2*)(cof + (size_t)row * (TAPS * 2));
    float hre[TAPS], him[TAPS];
    #pragma unroll
    for (int l = 0; l < TAPS; ++l) {
        float2 tv = ct[l];
        hre[l] = rfl(tv.x);
        him[l] = rfl(tv.y);
    }
    __syncthreads();

    float2* go2 = (float2*)(out0 + (size_t)row * (OUTLEN * 2));

    // ---- main: outputs t = 4*tid+1+1024*j + k, k<4  (covers t in [1,2048]) ----
    // Chunk c taps l=8c..8c+7: window = 6 lane-contiguous ds_read_b128 (linear,
    // conflict-free); all q indices compile-time.
    #pragma unroll 1
    for (int j = 0; j < 2; ++j) {
        const int tf = 4 * tid + 1 + 1024 * j;

        v2f accA[4], accB[4];
        #pragma unroll
        for (int k = 0; k < 4; ++k) { accA[k] = (v2f)(0.f); accB[k] = (v2f)(0.f); }

        #pragma unroll
        for (int c = 0; c < 4; ++c) {
            // window float2 slots [32+tf-8c-7, 32+tf-8c+3]; start even ->
            // float4 base = 2*tid + 512*j - 4*c + 13 (always odd, 16B aligned)
            const int base4 = 2 * tid + 512 * j - 4 * c + 13;
            float4 w4[6];
            #pragma unroll
            for (int i = 0; i < 6; ++i) w4[i] = S4[base4 + i];

            #pragma unroll
            for (int lp = 0; lp < 8; ++lp) {
                const int l = 8 * c + lp;
                const v2f hv = { hre[l], him[l] };       // SGPR pair, uniform
                #pragma unroll
                for (int k = 0; k < 4; ++k) {
                    const int q = k - lp + 7;            // 0..10, compile-time
                    const float sx = (q & 1) ? w4[q >> 1].z : w4[q >> 1].x;
                    const float sy = (q & 1) ? w4[q >> 1].w : w4[q >> 1].y;
                    accA[k] = __builtin_elementwise_fma((v2f){ sx, sx }, hv, accA[k]);
                    accB[k] = __builtin_elementwise_fma((v2f){ sy, sy }, hv, accB[k]);
                }
            }
            // contain chunk live-ranges (don't hoist next chunk's 6 reads)
            __builtin_amdgcn_sched_barrier(0);
        }

        #pragma unroll
        for (int k = 0; k < 4; ++k)
            go2[tf + k] = make_float2(accA[k].x - accB[k].y, accA[k].y + accB[k].x);
    }

    const float2* S2 = (const float2*)S4;

    // ---- wave 0 extra: fused 64-pt DFT of zero-padded taps ----
    if (tid < MDFT) {
        const int kk = tid;
        v2f aA = (v2f)(0.f), aB = (v2f)(0.f);
        #pragma unroll
        for (int l = 0; l < TAPS; ++l) {
            const v2f hv = { hre[l], him[l] };
            float2 w = s_tw[(kk * l) & (MDFT - 1)];
            aA = __builtin_elementwise_fma((v2f){ w.x, w.x }, hv, aA);
            aB = __builtin_elementwise_fma((v2f){ w.y, w.y }, hv, aB);
        }
        ((float2*)out1)[(size_t)row * MDFT + kk] =
            make_float2(aA.x - aB.y, aA.y + aB.x);
    }
    // ---- wave 2 extra: leftover outputs t=0 and t=2049..2078 ----
    else if (tid >= 128 && tid <= 158) {
        const int t = (tid == 158) ? 0 : (2049 + (tid - 128));
        v2f aA = (v2f)(0.f), aB = (v2f)(0.f);
        #pragma unroll
        for (int l = 0; l < TAPS; ++l) {
            const v2f hv = { hre[l], him[l] };
            float2 s = S2[PAD + t - l];      // pads supply zeros both ends
            aA = __builtin_elementwise_fma((v2f){ s.x, s.x }, hv, aA);
            aB = __builtin_elementwise_fma((v2f){ s.y, s.y }, hv, aB);
        }
        go2[t] = make_float2(aA.x - aB.y, aA.y + aB.x);
    }
}

extern "C" void kernel_launch(void* const* d_in, const int* in_sizes, int n_in,
                              void* d_out, int out_size, void* d_ws, size_t ws_size,
                              hipStream_t stream)
{
    const float* input = (const float*)d_in[0];  // (N,P,2048,2) fp32
    const float* cof   = (const float*)d_in[1];  // (N,P,32,2)   fp32
    // d_in[2] is M (=64), compile-time here.

    const int NP = in_sizes[0] / (SMK * 2);      // 16384

    float* out0 = (float*)d_out;                           // (NP, 2079, 2)
    float* out1 = out0 + (size_t)NP * OUTLEN * 2;          // (NP, 64, 2)

    conv_kernel<<<NP, 256, 0, stream>>>(input, cof, out0, out1);
}